// Round 1
// baseline (339.421 us; speedup 1.0000x reference)
//
#include <hip/hip_runtime.h>
#include <hip/hip_bf16.h>

typedef unsigned short u16;
typedef __hip_bfloat16 bf16_t;
typedef __attribute__((ext_vector_type(8))) short short8;
typedef __attribute__((ext_vector_type(4))) float floatx4;

#define MDIM 4096
#define NDIM 4096
#define KDIM 4096
#define BM 128
#define BN 128
#define BK 32

// ---------------- fp32 -> bf16 conversion (memory-bound) ----------------
__global__ __launch_bounds__(256) void cvt_f32_bf16(const float* __restrict__ src,
                                                    u16* __restrict__ dst, int n8) {
    int i = blockIdx.x * blockDim.x + threadIdx.x;
    if (i >= n8) return;
    const float4* s = (const float4*)src;
    float4 f0 = s[(size_t)i * 2];
    float4 f1 = s[(size_t)i * 2 + 1];
    float vals[8] = {f0.x, f0.y, f0.z, f0.w, f1.x, f1.y, f1.z, f1.w};
    union { u16 u[8]; uint4 v; } o;
#pragma unroll
    for (int j = 0; j < 8; ++j) {
        bf16_t h = __float2bfloat16(vals[j]);   // RNE
        u16 b;
        __builtin_memcpy(&b, &h, 2);
        o.u[j] = b;
    }
    ((uint4*)dst)[i] = o.v;
}

// ---------------- bf16 GEMM, C = A * B^T + bias (m97 structure) ----------------
// A: M x K (row-major, K-contig), B: N x K (row-major, K-contig) == W
// 128x128 block tile, BK=32, 256 threads = 4 waves, each wave 64x64 (4x4 MFMA tiles)
typedef const __attribute__((address_space(1))) void* gas_ptr;
typedef __attribute__((address_space(3))) void* lds_ptr;

__global__ __launch_bounds__(256) void gemm_bt_bias(const u16* __restrict__ A,
                                                    const u16* __restrict__ B,
                                                    const float* __restrict__ bias,
                                                    float* __restrict__ C) {
    // NO padding: global_load_lds writes wave-uniform base + lane*16B; the
    // row-major [r][k] layout matches thread t -> elem offset 8*t exactly.
    __shared__ u16 lA[BM * BK];  // 8 KiB
    __shared__ u16 lB[BN * BK];  // 8 KiB

    const int t = threadIdx.x;
    const int bm0 = blockIdx.y * BM;
    const int bn0 = blockIdx.x * BN;

    const int wave = t >> 6;
    const int lane = t & 63;
    const int wm = (wave & 1) * 64;
    const int wn = (wave >> 1) * 64;
    const int lr = lane & 15;          // m (A) / n (B) within 16
    const int kq = (lane >> 4) * 8;    // k offset 0/8/16/24

    floatx4 acc[4][4] = {};

    // staging mapping: thread t -> row r = t/4 (plus 64 for 2nd half), k chunk (t%4)*8
    const int r = t >> 2;
    const int c = (t & 3) * 8;
    const u16* gA0 = A + (size_t)(bm0 + r) * KDIM + c;
    const u16* gA1 = A + (size_t)(bm0 + 64 + r) * KDIM + c;
    const u16* gB0 = B + (size_t)(bn0 + r) * KDIM + c;
    const u16* gB1 = B + (size_t)(bn0 + 64 + r) * KDIM + c;
    u16* lA0 = &lA[(size_t)t * 8];
    u16* lA1 = &lA[2048 + (size_t)t * 8];
    u16* lB0 = &lB[(size_t)t * 8];
    u16* lB1 = &lB[2048 + (size_t)t * 8];

    for (int k0 = 0; k0 < KDIM; k0 += BK) {
        __builtin_amdgcn_global_load_lds((gas_ptr)(gA0 + k0), (lds_ptr)lA0, 16, 0, 0);
        __builtin_amdgcn_global_load_lds((gas_ptr)(gA1 + k0), (lds_ptr)lA1, 16, 0, 0);
        __builtin_amdgcn_global_load_lds((gas_ptr)(gB0 + k0), (lds_ptr)lB0, 16, 0, 0);
        __builtin_amdgcn_global_load_lds((gas_ptr)(gB1 + k0), (lds_ptr)lB1, 16, 0, 0);
        __syncthreads();  // drains vmcnt (global_load_lds) before reads

        short8 af[4], bfr[4];
#pragma unroll
        for (int i = 0; i < 4; ++i)
            af[i] = *(const short8*)&lA[(wm + i * 16 + lr) * BK + kq];
#pragma unroll
        for (int j = 0; j < 4; ++j)
            bfr[j] = *(const short8*)&lB[(wn + j * 16 + lr) * BK + kq];

#pragma unroll
        for (int i = 0; i < 4; ++i)
#pragma unroll
            for (int j = 0; j < 4; ++j)
                acc[i][j] = __builtin_amdgcn_mfma_f32_16x16x32_bf16(af[i], bfr[j], acc[i][j], 0, 0, 0);
        __syncthreads();  // protect LDS before next-iter staging overwrite
    }

    // epilogue: C/D layout col=lane&15, row=(lane>>4)*4+q  [m89-verified]
#pragma unroll
    for (int i = 0; i < 4; ++i) {
        const int row0 = bm0 + wm + i * 16 + (lane >> 4) * 4;
#pragma unroll
        for (int j = 0; j < 4; ++j) {
            const int col = bn0 + wn + j * 16 + lr;
            const float bv = bias[col];
#pragma unroll
            for (int q = 0; q < 4; ++q)
                C[(size_t)(row0 + q) * NDIM + col] = acc[i][j][q] + bv;
        }
    }
}

extern "C" void kernel_launch(void* const* d_in, const int* in_sizes, int n_in,
                              void* d_out, int out_size, void* d_ws, size_t ws_size,
                              hipStream_t stream) {
    const float* x = (const float*)d_in[0];      // (4096, 4096) fp32
    const float* w = (const float*)d_in[1];      // (4096, 4096) fp32, OUT x IN
    const float* bias = (const float*)d_in[2];   // (4096,) fp32
    float* out = (float*)d_out;                  // (4096, 4096) fp32

    u16* xa = (u16*)d_ws;                        // 32 MiB bf16 x
    u16* wb = xa + (size_t)MDIM * KDIM;          // 32 MiB bf16 W

    const int n8 = (MDIM * KDIM) / 8;            // 2,097,152
    cvt_f32_bf16<<<n8 / 256, 256, 0, stream>>>(x, xa, n8);
    cvt_f32_bf16<<<n8 / 256, 256, 0, stream>>>(w, wb, n8);

    dim3 grid(NDIM / BN, MDIM / BM);             // 32 x 32
    gemm_bt_bias<<<grid, dim3(256), 0, stream>>>(xa, wb, bias, out);
}